// Round 14
// baseline (265.929 us; speedup 1.0000x reference)
//
#include <hip/hip_runtime.h>
#include <hip/hip_bf16.h>

#define B_   8
#define C_   128
#define H_   96
#define W_   96
#define HP_  98            // padded H/W
#define HO_  48
#define N_   2304          // HO_*HO_
#define K_CONV 1152        // C_*9
#define PLANE_IN  9216     // H_*W_
#define TOT_OUT (B_*C_*N_)
#define LOG2E 1.4426950408889634f

typedef __attribute__((ext_vector_type(8))) short          s16x8;
typedef __attribute__((ext_vector_type(8))) unsigned short u16x8;
typedef __attribute__((ext_vector_type(4))) unsigned short u16x4;
typedef __attribute__((ext_vector_type(4))) float          f32x4;

// XOR-swizzled byte offsets for bf16 LDS tiles, 16 B granules
#define SW(row, q)   (((row) << 6) + ((((q) ^ (((row) >> 1) & 3))) << 4))   // 64 B rows
#define SW8(row, q)  (((row) << 7) + ((((q) ^ ((row) & 7))) << 4))           // 128 B rows
#define SW16(row, q) (((row) << 8) + ((((q) ^ ((row) & 15))) << 4))          // 256 B rows

// native gfx950 transcendentals: v_exp_f32 = 2^x, v_log_f32 = log2(x)
__device__ __forceinline__ float fexp2(float x) { return __builtin_amdgcn_exp2f(x); }
__device__ __forceinline__ float flog2(float x) { return __builtin_amdgcn_logf(x); }

__device__ __forceinline__ ushort f2bf(float f) {
  __hip_bfloat16 h = __float2bfloat16(f);
  return *reinterpret_cast<ushort*>(&h);
}

// ------- conv weights fp32 OIHW -> bf16 [co][(kh*3+kw)*128+ci], 3 branches --
// tail block (x == 576, y == 0) computes the BN inv/beta params.
__global__ __launch_bounds__(256) void k_prep_w(
    const float* __restrict__ w0, const float* __restrict__ w1, const float* __restrict__ w2,
    ushort* __restrict__ o0, ushort* __restrict__ o1, ushort* __restrict__ o2,
    const float* __restrict__ bw0, const float* __restrict__ bb0,
    const float* __restrict__ bm0, const float* __restrict__ bv0,
    const float* __restrict__ bw1, const float* __restrict__ bb1,
    const float* __restrict__ bm1, const float* __restrict__ bv1,
    const float* __restrict__ bw2, const float* __restrict__ bb2,
    const float* __restrict__ bm2, const float* __restrict__ bv2,
    float* __restrict__ pinv, float* __restrict__ pbeta) {
  int p = blockIdx.y;
  if (blockIdx.x == (C_ * K_CONV) / 256) {   // tail: BN param prep
    if (p == 0 && threadIdx.x < 128) {
      int c = threadIdx.x;
      const float* ws[3] = {bw0, bw1, bw2};
      const float* bs[3] = {bb0, bb1, bb2};
      const float* ms[3] = {bm0, bm1, bm2};
      const float* vs[3] = {bv0, bv1, bv2};
      #pragma unroll
      for (int pb = 0; pb < 3; ++pb) {
        float iv = ws[pb][c] / sqrtf(vs[pb][c] + 1e-5f);
        pinv[pb * 128 + c] = iv;
        pbeta[pb * 128 + c] = bs[pb][c] - ms[pb][c] * iv;
      }
    }
    return;
  }
  const float* w = (p == 0 ? w0 : p == 1 ? w1 : w2);
  ushort* wb = (p == 0 ? o0 : p == 1 ? o1 : o2);
  int id = blockIdx.x * 256 + threadIdx.x;
  int co = id / K_CONV, rem = id - co * K_CONV;
  int tap = rem >> 7, ci = rem & 127;
  wb[id] = f2bf(w[co * K_CONV + ci * 9 + tap]);
}

// ------- x -> 3x padded NHWC bf16 y (BN+ReLU fused) + x channel-sums --------
__global__ __launch_bounds__(256) void k_prep_y(const float* __restrict__ x,
                                                const float* __restrict__ pinv,
                                                const float* __restrict__ pbeta,
                                                ushort* __restrict__ y0,
                                                ushort* __restrict__ y1,
                                                ushort* __restrict__ y2,
                                                float* __restrict__ wcat) {
  const int h1 = blockIdx.x, b = blockIdx.y, t = threadIdx.x;
  ushort* ys[3] = {y0 + (size_t)b * HP_ * HP_ * C_,
                   y1 + (size_t)b * HP_ * HP_ * C_,
                   y2 + (size_t)b * HP_ * HP_ * C_};
  u16x8 zer = (u16x8)0;
  if (h1 == 0 || h1 == HP_ - 1) {
    for (int p = 0; p < 3; ++p)
      for (int g = t; g < HP_ * C_ / 8; g += 256)
        *(u16x8*)(ys[p] + (size_t)h1 * HP_ * C_ + g * 8) = zer;
    return;
  }
  __shared__ float xs[128][97];
  const int h = h1 - 1;
  const float* xb = x + (size_t)b * C_ * PLANE_IN + h * W_;
  for (int id = t; id < 128 * 24; id += 256) {
    int ci = id / 24, w4 = id - ci * 24;
    float4 v = *(const float4*)(xb + (size_t)ci * PLANE_IN + w4 * 4);
    xs[ci][w4 * 4 + 0] = v.x; xs[ci][w4 * 4 + 1] = v.y;
    xs[ci][w4 * 4 + 2] = v.z; xs[ci][w4 * 4 + 3] = v.w;
  }
  __syncthreads();
  if (t < 128) {               // x channel-sum for SE
    float s = 0.f;
    #pragma unroll
    for (int k = 0; k < 96; ++k) s += xs[t][k];
    atomicAdd(&wcat[b * 256 + t], s);
  }
  if (t >= 128 && t < 160) {
    int tt = t - 128;
    int side = tt >> 4, cg = tt & 15;
    for (int p = 0; p < 3; ++p)
      *(u16x8*)(ys[p] + ((size_t)h1 * HP_ + (side ? HP_ - 1 : 0)) * C_ + cg * 8) = zer;
  }
  for (int p = 0; p < 3; ++p) {
    const float* inv = pinv + p * 128;
    const float* bet = pbeta + p * 128;
    for (int g = t; g < 96 * 16; g += 256) {
      int wdx = g >> 4, cg = g & 15;
      u16x8 o;
      #pragma unroll
      for (int k = 0; k < 8; ++k) {
        int ci = cg * 8 + k;
        o[k] = f2bf(fmaxf(xs[ci][wdx] * inv[ci] + bet[ci], 0.f));
      }
      *(u16x8*)(ys[p] + ((size_t)h1 * HP_ + (wdx + 1)) * C_ + cg * 8) = o;
    }
  }
}

// ------- merged MFMA conv (3 branches): grid (18, 3, 8) ---------------------
// 128co x 128n tile, 4 waves each 64co x 64n (16 MFMA/iter/wave).
// As/Bs double-buffered 4 x 8 KB = 32 KB; pipelined, one barrier/iter.
// Output scales: br0 *log2e, br2 *gamma.
__global__ __launch_bounds__(256) void k_conv3(
    const ushort* __restrict__ y0, const ushort* __restrict__ y1, const ushort* __restrict__ y2,
    const ushort* __restrict__ w0, const ushort* __restrict__ w1, const ushort* __restrict__ w2,
    const float* __restrict__ bi0, const float* __restrict__ bi1, const float* __restrict__ bi2,
    const float* __restrict__ gammap,
    ushort* __restrict__ fo, ushort* __restrict__ go, ushort* __restrict__ ho) {
  __shared__ __align__(16) char smem[32768];
  // As dbuf at 0/8192 ; Bs dbuf at 16384/24576
  const int br = blockIdx.y, b = blockIdx.z, n0 = blockIdx.x * 128;
  const int t = threadIdx.x, l = t & 63, w = t >> 6;
  const ushort* yb = (br == 0 ? y0 : br == 1 ? y1 : y2) + (size_t)b * HP_ * HP_ * C_;
  const ushort* wb = (br == 0 ? w0 : br == 1 ? w1 : w2);
  const float* bias = (br == 0 ? bi0 : br == 1 ? bi1 : bi2);
  const float gm = (br == 2) ? gammap[0] : (br == 0 ? LOG2E : 1.f);
  const int pos0 = t >> 2, q4 = t & 3;
  const int ng0 = n0 + pos0,       oh0 = ng0 / HO_, ow0 = ng0 - oh0 * HO_;
  const int ng1 = n0 + pos0 + 64,  oh1 = ng1 / HO_, ow1 = ng1 - oh1 * HO_;
  const int mh = (w & 1) * 64, nh = (w >> 1) * 64;
  f32x4 acc[4][4];
  #pragma unroll
  for (int i = 0; i < 4; ++i)
    #pragma unroll
    for (int j = 0; j < 4; ++j) acc[i][j] = (f32x4)0.f;

  u16x8 sA0, sA1, sB0, sB1;
  auto LD = [&](int k0) {
    int tap = k0 >> 7, ci0 = k0 & 127;
    int kh = tap / 3, kw = tap - kh * 3;
    sA0 = *(const u16x8*)(wb + (size_t)pos0 * K_CONV + k0 + q4 * 8);
    sA1 = *(const u16x8*)(wb + (size_t)(pos0 + 64) * K_CONV + k0 + q4 * 8);
    sB0 = *(const u16x8*)(yb + ((size_t)(2 * oh0 + kh) * HP_ + 2 * ow0 + kw) * C_ + ci0 + q4 * 8);
    sB1 = *(const u16x8*)(yb + ((size_t)(2 * oh1 + kh) * HP_ + 2 * ow1 + kw) * C_ + ci0 + q4 * 8);
  };
  auto ST = [&](char* As, char* Bs) {
    *(u16x8*)(As + SW(pos0, q4)) = sA0;
    *(u16x8*)(As + SW(pos0 + 64, q4)) = sA1;
    *(u16x8*)(Bs + SW(pos0, q4)) = sB0;
    *(u16x8*)(Bs + SW(pos0 + 64, q4)) = sB1;
  };

  LD(0);
  ST(smem, smem + 16384);
  __syncthreads();
  for (int s = 0; s < 36; ++s) {
    char* Asc = smem + ((s & 1) << 13);
    char* Bsc = smem + 16384 + ((s & 1) << 13);
    if (s < 35) LD((s + 1) * 32);          // issue early (T14)
    s16x8 af[4], bf[4];
    #pragma unroll
    for (int i = 0; i < 4; ++i) {
      int r = mh + i * 16 + (l & 15);
      af[i] = *(const s16x8*)(Asc + SW(r, (l >> 4)));
    }
    #pragma unroll
    for (int j = 0; j < 4; ++j) {
      int r = nh + j * 16 + (l & 15);
      bf[j] = *(const s16x8*)(Bsc + SW(r, (l >> 4)));
    }
    __builtin_amdgcn_s_setprio(1);
    #pragma unroll
    for (int i = 0; i < 4; ++i)
      #pragma unroll
      for (int j = 0; j < 4; ++j)
        acc[i][j] = __builtin_amdgcn_mfma_f32_16x16x32_bf16(af[i], bf[j], acc[i][j], 0, 0, 0);
    __builtin_amdgcn_s_setprio(0);
    if (s < 35)
      ST(smem + (((s + 1) & 1) << 13), smem + 16384 + (((s + 1) & 1) << 13));
    __syncthreads();
  }

  if (br < 2) {  // out[b][n][c] via LDS bounce (br0 scaled by log2e)
    ushort* out = (br == 0) ? fo : go;
    ushort* tb = (ushort*)smem;  // [128 pos][128 co] = 32 KB
    #pragma unroll
    for (int i = 0; i < 4; ++i) {
      int co4 = mh + i * 16 + (l >> 4) * 4;
      float4 bi = *(const float4*)&bias[co4];
      float bia[4] = {bi.x, bi.y, bi.z, bi.w};
      #pragma unroll
      for (int j = 0; j < 4; ++j) {
        int pp = nh + j * 16 + (l & 15);
        #pragma unroll
        for (int r = 0; r < 4; ++r)
          tb[pp * 128 + co4 + r] = f2bf((acc[i][j][r] + bia[r]) * gm);
      }
    }
    __syncthreads();
    #pragma unroll
    for (int it = 0; it < 8; ++it) {
      int g = t + it * 256;
      int row = g >> 4, gg = g & 15;
      u16x8 d = *(const u16x8*)(tb + row * 128 + gg * 8);
      *(u16x8*)(out + ((size_t)b * N_ + n0 + row) * C_ + gg * 8) = d;
    }
  } else {       // out[b][c][n] via LDS bounce, gamma folded
    ushort* tb = (ushort*)smem;  // [128 co][128 pos] = 32 KB
    #pragma unroll
    for (int i = 0; i < 4; ++i) {
      int co4 = mh + i * 16 + (l >> 4) * 4;
      float4 bi = *(const float4*)&bias[co4];
      float bia[4] = {bi.x, bi.y, bi.z, bi.w};
      #pragma unroll
      for (int j = 0; j < 4; ++j) {
        int pp = nh + j * 16 + (l & 15);
        #pragma unroll
        for (int r = 0; r < 4; ++r)
          tb[(co4 + r) * 128 + pp] = f2bf((acc[i][j][r] + bia[r]) * gm);
      }
    }
    __syncthreads();
    #pragma unroll
    for (int it = 0; it < 8; ++it) {
      int g = t + it * 256;
      int co = g >> 4, off2 = (g & 15) * 8;
      u16x8 d = *(const u16x8*)(tb + co * 128 + off2);
      *(u16x8*)(ho + ((size_t)b * C_ + co) * N_ + n0 + off2) = d;
    }
  }
}

// ------- pass 1: partial row stats over m-chunk; grid 576 (XCD swizzle) -----
// v5: 128 n-rows per block (af[2][4]) -> 32 MFMA per staged gs tile; staging
// bytes + barriers per MFMA halved; bf LDS loads shared between row-sets.
__global__ __launch_bounds__(256) void k_stats(const ushort* __restrict__ f,
                                               const ushort* __restrict__ g,
                                               float2* __restrict__ pstats) {
  __shared__ __align__(16) char smem[32768];   // gs double buffer 2 x 16 KB
  const int blk = blockIdx.x;
  const int b = blk & 7, t2 = blk >> 3;
  const int n0 = (t2 % 18) * 128, mz = t2 / 18;
  const int t = threadIdx.x, l = t & 63, w = t >> 6, lo = l & 15, quad = l >> 4;
  const ushort* fb = f + (size_t)b * N_ * C_;
  const ushort* gb = g + (size_t)b * N_ * C_;
  s16x8 af[2][4];
  #pragma unroll
  for (int ii = 0; ii < 2; ++ii)
    #pragma unroll
    for (int ks = 0; ks < 4; ++ks)
      af[ii][ks] = *(const s16x8*)(fb + (size_t)(n0 + ii * 64 + w * 16 + lo) * C_ + (ks * 4 + quad) * 8);
  float mloc[2][4], lloc[2][4];
  #pragma unroll
  for (int ii = 0; ii < 2; ++ii)
    #pragma unroll
    for (int r = 0; r < 4; ++r) { mloc[ii][r] = -1e30f; lloc[ii][r] = 0.f; }
  const int m_beg = mz * 576;

  u16x8 st[4];
  #pragma unroll
  for (int it = 0; it < 4; ++it) {
    int G = t + it * 256, row = G >> 4, g16 = G & 15;
    st[it] = *(const u16x8*)(gb + (size_t)(m_beg + row) * C_ + g16 * 8);
  }
  #pragma unroll
  for (int it = 0; it < 4; ++it) {
    int G = t + it * 256, row = G >> 4, g16 = G & 15;
    *(u16x8*)(smem + SW16(row, g16)) = st[it];
  }
  __syncthreads();

  #pragma unroll
  for (int i9 = 0; i9 < 9; ++i9) {
    char* gs = smem + ((i9 & 1) << 14);
    if (i9 < 8) {
      int m0n = m_beg + (i9 + 1) * 64;
      #pragma unroll
      for (int it = 0; it < 4; ++it) {
        int G = t + it * 256, row = G >> 4, g16 = G & 15;
        st[it] = *(const u16x8*)(gb + (size_t)(m0n + row) * C_ + g16 * 8);
      }
    }
    f32x4 acc[2][4];
    #pragma unroll
    for (int ii = 0; ii < 2; ++ii)
      #pragma unroll
      for (int j = 0; j < 4; ++j) acc[ii][j] = (f32x4)0.f;
    __builtin_amdgcn_s_setprio(1);
    #pragma unroll
    for (int ks = 0; ks < 4; ++ks)
      #pragma unroll
      for (int j = 0; j < 4; ++j) {
        s16x8 bf = *(const s16x8*)(gs + SW16(j * 16 + lo, ks * 4 + quad));
        acc[0][j] = __builtin_amdgcn_mfma_f32_16x16x32_bf16(af[0][ks], bf, acc[0][j], 0, 0, 0);
        acc[1][j] = __builtin_amdgcn_mfma_f32_16x16x32_bf16(af[1][ks], bf, acc[1][j], 0, 0, 0);
      }
    __builtin_amdgcn_s_setprio(0);
    #pragma unroll
    for (int ii = 0; ii < 2; ++ii)
      #pragma unroll
      for (int r = 0; r < 4; ++r) {
        float vmax = fmaxf(fmaxf(acc[ii][0][r], acc[ii][1][r]),
                           fmaxf(acc[ii][2][r], acc[ii][3][r]));
        float mn = fmaxf(mloc[ii][r], vmax);
        lloc[ii][r] = lloc[ii][r] * fexp2(mloc[ii][r] - mn) +
                      fexp2(acc[ii][0][r] - mn) + fexp2(acc[ii][1][r] - mn) +
                      fexp2(acc[ii][2][r] - mn) + fexp2(acc[ii][3][r] - mn);
        mloc[ii][r] = mn;
      }
    if (i9 < 8) {
      char* gn = smem + (((i9 + 1) & 1) << 14);
      #pragma unroll
      for (int it = 0; it < 4; ++it) {
        int G = t + it * 256, row = G >> 4, g16 = G & 15;
        *(u16x8*)(gn + SW16(row, g16)) = st[it];
      }
    }
    __syncthreads();
  }
  #pragma unroll
  for (int ii = 0; ii < 2; ++ii)
    #pragma unroll
    for (int r = 0; r < 4; ++r) {
      #pragma unroll
      for (int o = 1; o < 16; o <<= 1) {
        float mo = __shfl_xor(mloc[ii][r], o, 64);
        float lo2 = __shfl_xor(lloc[ii][r], o, 64);
        float mn = fmaxf(mloc[ii][r], mo);
        lloc[ii][r] = lloc[ii][r] * fexp2(mloc[ii][r] - mn) + lo2 * fexp2(mo - mn);
        mloc[ii][r] = mn;
      }
    }
  if (lo == 0) {
    #pragma unroll
    for (int ii = 0; ii < 2; ++ii)
      #pragma unroll
      for (int r = 0; r < 4; ++r)
        pstats[((size_t)mz * B_ + b) * N_ + n0 + ii * 64 + w * 16 + quad * 4 + r] =
            make_float2(mloc[ii][r], lloc[ii][r]);
  }
}

// ------- merge 4 partial stats -> a[n] = -mx2 - log2(l2)  (exp2 domain) -----
__global__ __launch_bounds__(256) void k_stats_red(const float2* __restrict__ p,
                                                   float* __restrict__ astat) {
  int idx = blockIdx.x * 256 + threadIdx.x;   // b*N+n
  if (idx >= B_ * N_) return;
  float mx = -1e30f, ls = 0.f;
  #pragma unroll
  for (int z = 0; z < 4; ++z) {
    float2 s = p[(size_t)z * B_ * N_ + idx];
    float mn = fmaxf(mx, s.x);
    ls = ls * fexp2(mx - mn) + s.y * fexp2(s.x - mn);
    mx = mn;
  }
  astat[idx] = -mx - flog2(ls);
}

// ------- pass 2: fused scores+softmax+PV partials; grid 1152 (XCD swizzle) --
// v8: s-row sums computed INSIDE the ss-bounce loop (accs dead by then).
__global__ __launch_bounds__(256) void k_attn_out(const ushort* __restrict__ f,
                                                  const ushort* __restrict__ g,
                                                  const ushort* __restrict__ h,
                                                  const float* __restrict__ astat,
                                                  float* __restrict__ spart,
                                                  float* __restrict__ wcat) {
  __shared__ __align__(16) char smem[32768];
  char* gs = smem;            // [64 m][128 c] SW16 16 KB (staged once)
  char* pTb = smem + 16384;   // pT double buffer 2 x 8 KB
  const int blk = blockIdx.x;
  const int b = blk & 7, t2 = blk >> 3;
  const int m0 = (t2 % 36) * 64, nz = t2 / 36;
  const int t = threadIdx.x, l = t & 63, w = t >> 6, lo = l & 15, quad = l >> 4;
  const ushort* fb = f + (size_t)b * N_ * C_;
  const ushort* gb = g + (size_t)b * N_ * C_;
  const ushort* hb = h + (size_t)b * C_ * N_;
  const float* ab = astat + (size_t)b * N_;
  #pragma unroll
  for (int it = 0; it < 4; ++it) {   // gs: 1024 granules, once
    int G = t + it * 256, row = G >> 4, g16 = G & 15;
    *(u16x8*)(gs + SW16(row, g16)) = *(const u16x8*)(gb + (size_t)(m0 + row) * C_ + g16 * 8);
  }
  f32x4 accs[2][4];
  #pragma unroll
  for (int i = 0; i < 2; ++i)
    #pragma unroll
    for (int j = 0; j < 4; ++j) accs[i][j] = (f32x4)0.f;
  const int n_beg = nz * 576;

  s16x8 af[2][4];
  s16x8 ahc[2][2];
  float ax[2][4];

  auto LOAD_AF = [&](int i, int p) {
    int nb = n_beg + i * 64;
    #pragma unroll
    for (int ks = 0; ks < 4; ++ks)
      af[p][ks] = *(const s16x8*)(fb + (size_t)(nb + w * 16 + lo) * C_ + (ks * 4 + quad) * 8);
    float4 av = *(const float4*)(ab + nb + w * 16 + quad * 4);
    ax[p][0] = av.x; ax[p][1] = av.y; ax[p][2] = av.z; ax[p][3] = av.w;
  };
  auto LOAD_AH = [&](int i) {
    int nb = n_beg + i * 64;
    #pragma unroll
    for (int ii = 0; ii < 2; ++ii)
      #pragma unroll
      for (int ks = 0; ks < 2; ++ks)
        ahc[ii][ks] = *(const s16x8*)(hb + (size_t)((2 * w + ii) * 16 + lo) * N_ + nb + (ks * 4 + quad) * 8);
  };
  auto QKEXP = [&](int p) {
    char* pT = pTb + (p << 13);
    f32x4 sc[4];
    #pragma unroll
    for (int j = 0; j < 4; ++j) sc[j] = (f32x4)0.f;
    __builtin_amdgcn_s_setprio(1);
    #pragma unroll
    for (int ks = 0; ks < 4; ++ks)
      #pragma unroll
      for (int j = 0; j < 4; ++j) {
        s16x8 bg = *(const s16x8*)(gs + SW16(j * 16 + lo, ks * 4 + quad));
        sc[j] = __builtin_amdgcn_mfma_f32_16x16x32_bf16(af[p][ks], bg, sc[j], 0, 0, 0);
      }
    __builtin_amdgcn_s_setprio(0);
    const int nl = w * 16 + quad * 4;
    #pragma unroll
    for (int j = 0; j < 4; ++j) {
      u16x4 pv;
      #pragma unroll
      for (int r = 0; r < 4; ++r)
        pv[r] = f2bf(fexp2(sc[j][r] + ax[p][r]));
      *(u16x4*)(pT + SW8(j * 16 + lo, nl >> 3) + (nl & 7) * 2) = pv;
    }
  };
  auto PV = [&](int p) {
    char* pT = pTb + (p << 13);
    __builtin_amdgcn_s_setprio(1);
    #pragma unroll
    for (int ks = 0; ks < 2; ++ks)
      #pragma unroll
      for (int j = 0; j < 4; ++j) {
        s16x8 bp = *(const s16x8*)(pT + SW8(j * 16 + lo, ks * 4 + quad));
        accs[0][j] = __builtin_amdgcn_mfma_f32_16x16x32_bf16(ahc[0][ks], bp, accs[0][j], 0, 0, 0);
        accs[1][j] = __builtin_amdgcn_mfma_f32_16x16x32_bf16(ahc[1][ks], bp, accs[1][j], 0, 0, 0);
      }
    __builtin_amdgcn_s_setprio(0);
  };

  LOAD_AF(0, 0);
  LOAD_AH(0);
  __syncthreads();           // gs staged
  QKEXP(0);                  // writes pT[0]
  LOAD_AF(1, 1);
  #pragma unroll
  for (int i9 = 0; i9 < 9; ++i9) {
    __syncthreads();         // pT[i9&1] published
    PV(i9 & 1);
    if (i9 < 8) {
      LOAD_AH(i9 + 1);
      QKEXP((i9 + 1) & 1);
      if (i9 < 7) LOAD_AF(i9 + 2, i9 & 1);
    }
  }
  // epilogue: two-chunk f32 transpose bounce -> 256B-coalesced float4 stores.
  // s-row sums from the loaded float4s (16 consecutive lanes share ci).
  float* outp = spart + (size_t)nz * TOT_OUT + (size_t)b * C_ * N_ + m0;
  float* ss = (float*)smem;   // [64 rows][68] f32 = 17408 B (gs/pT dead)
  #pragma unroll
  for (int ch = 0; ch < 2; ++ch) {
    __syncthreads();          // pT reads done / prior chunk stores done
    {
      int ci0 = w * 16 + quad * 4;
      #pragma unroll
      for (int j = 0; j < 4; ++j) {
        int m = j * 16 + lo;
        #pragma unroll
        for (int r = 0; r < 4; ++r)
          ss[(ci0 + r) * 68 + m] = accs[ch][j][r];
      }
    }
    __syncthreads();
    #pragma unroll
    for (int it = 0; it < 4; ++it) {
      int idx = t + it * 256;
      int ci = idx >> 4, mq = idx & 15;
      int c = (ci >> 4) * 32 + ch * 16 + (ci & 15);
      float4 v = *(const float4*)&ss[ci * 68 + mq * 4];
      *(float4*)&outp[(size_t)c * N_ + mq * 4] = v;
      float sm = (v.x + v.y) + (v.z + v.w);
      #pragma unroll
      for (int o = 1; o < 16; o <<= 1) sm += __shfl_xor(sm, o, 64);
      if (mq == 0) atomicAdd(&wcat[(b << 8) + 128 + c], sm);
    }
  }
}

// ---------------- SE MLP: 256 -> 42 (relu) -> 128 ---------------------------
// wcat holds RAW sums both halves: x-sums (prep_y) and s-sums (attn epilogue).
__global__ __launch_bounds__(128) void k_se(const float* __restrict__ wcat,
                                            const float* __restrict__ cw,
                                            const float* __restrict__ cb,
                                            const float* __restrict__ uw,
                                            const float* __restrict__ ub,
                                            float* __restrict__ se) {
  const int b = blockIdx.x, t = threadIdx.x;
  __shared__ float wc[256];
  __shared__ float s1[42];
  wc[t] = fmaxf(wcat[b * 256 + t] * (1.f / PLANE_IN), 0.f);
  wc[128 + t] = fmaxf(wcat[b * 256 + 128 + t] * (1.f / N_), 0.f);
  __syncthreads();
  if (t < 42) {
    float a = cb[t];
    const float* r = cw + (size_t)t * 256;
    for (int k = 0; k < 256; ++k) a += wc[k] * r[k];
    s1[t] = fmaxf(a, 0.f);
  }
  __syncthreads();
  {
    float a = ub[t];
    const float* r = uw + (size_t)t * 42;
    for (int j = 0; j < 42; ++j) a += s1[j] * r[j];
    se[b * 128 + t] = a;
  }
}

// ------- out = (avgpool2x2(x) + sum_z spart[z]) * (1 + se) ------------------
__global__ __launch_bounds__(256) void k_final(const float* __restrict__ x,
                                               const float* __restrict__ spart,
                                               const float* __restrict__ se,
                                               float* __restrict__ out) {
  int idx = blockIdx.x * 256 + threadIdx.x;
  if (idx >= TOT_OUT / 2) return;
  int m2 = idx % (N_ / 2);
  int bc = idx / (N_ / 2);
  int oh = m2 / (HO_ / 2), owp = m2 - oh * (HO_ / 2);
  size_t base = (size_t)bc * N_ + oh * HO_ + owp * 2;
  const float* xp = x + (size_t)bc * PLANE_IN;
  int ih = oh * 2, iw = owp * 4;
  float4 a = *(const float4*)(xp + ih * W_ + iw);
  float4 bb = *(const float4*)(xp + (ih + 1) * W_ + iw);
  float l0 = 0.25f * (a.x + a.y + bb.x + bb.y);
  float l1 = 0.25f * (a.z + a.w + bb.z + bb.w);
  float2 s0 = *(const float2*)(spart + base);
  float2 s1 = *(const float2*)(spart + (size_t)TOT_OUT + base);
  float2 s2 = *(const float2*)(spart + 2 * (size_t)TOT_OUT + base);
  float2 s3 = *(const float2*)(spart + 3 * (size_t)TOT_OUT + base);
  float sc = 1.f + se[bc];
  float2 o;
  o.x = (l0 + s0.x + s1.x + s2.x + s3.x) * sc;
  o.y = (l1 + s0.y + s1.y + s2.y + s3.y) * sc;
  *(float2*)(out + base) = o;
}

extern "C" void kernel_launch(void* const* d_in, const int* in_sizes, int n_in,
                              void* d_out, int out_size, void* d_ws, size_t ws_size,
                              hipStream_t stream) {
  (void)in_sizes; (void)n_in; (void)out_size; (void)ws_size;
  const float* x    = (const float*)d_in[0];
  const float* bnw[3] = {(const float*)d_in[1],  (const float*)d_in[7],  (const float*)d_in[13]};
  const float* bnb[3] = {(const float*)d_in[2],  (const float*)d_in[8],  (const float*)d_in[14]};
  const float* bnm[3] = {(const float*)d_in[3],  (const float*)d_in[9],  (const float*)d_in[15]};
  const float* bnv[3] = {(const float*)d_in[4],  (const float*)d_in[10], (const float*)d_in[16]};
  const float* cw_[3] = {(const float*)d_in[5],  (const float*)d_in[11], (const float*)d_in[17]};
  const float* cbb[3] = {(const float*)d_in[6],  (const float*)d_in[12], (const float*)d_in[18]};
  const float* secw = (const float*)d_in[19];
  const float* secb = (const float*)d_in[20];
  const float* seuw = (const float*)d_in[21];
  const float* seub = (const float*)d_in[22];
  const float* gamma = (const float*)d_in[23];
  float* out = (float*)d_out;

  char* ws = (char*)d_ws;
  size_t off = 0;
  auto alloc = [&](size_t bytes) -> char* {
    char* p = ws + off;
    off = (off + bytes + 255) & ~(size_t)255;
    return p;
  };
  ushort* yp[3];
  for (int p = 0; p < 3; ++p) yp[p] = (ushort*)alloc((size_t)B_ * HP_ * HP_ * C_ * 2);
  ushort* wb[3];
  for (int p = 0; p < 3; ++p) wb[p] = (ushort*)alloc((size_t)C_ * K_CONV * 2);
  ushort* fbuf = (ushort*)alloc((size_t)B_ * N_ * C_ * 2);       // [b][n][c], *log2e
  ushort* gbuf = (ushort*)alloc((size_t)B_ * N_ * C_ * 2);       // [b][n][c]
  ushort* hbuf = (ushort*)alloc((size_t)B_ * C_ * N_ * 2);       // [b][c][n], *gamma
  float2* pstats = (float2*)alloc((size_t)4 * B_ * N_ * 8);      // partial (mx2,l2)
  float*  astat  = (float*)alloc((size_t)B_ * N_ * 4);           // -mx2 - log2(l2)
  float*  spart = (float*)alloc((size_t)4 * TOT_OUT * 4);        // partial PV sums
  float*  wcat = (float*)alloc(B_ * 256 * 4);
  float*  sebuf = (float*)alloc(B_ * 128 * 4);
  float*  pinv  = (float*)alloc(3 * 128 * 4);
  float*  pbeta = (float*)alloc(3 * 128 * 4);

  hipMemsetAsync(wcat, 0, B_ * 256 * 4, stream);   // raw-sum accumulators

  k_prep_w<<<dim3((C_ * K_CONV) / 256 + 1, 3), 256, 0, stream>>>(
      cw_[0], cw_[1], cw_[2], wb[0], wb[1], wb[2],
      bnw[0], bnb[0], bnm[0], bnv[0],
      bnw[1], bnb[1], bnm[1], bnv[1],
      bnw[2], bnb[2], bnm[2], bnv[2], pinv, pbeta);
  k_prep_y<<<dim3(HP_, B_), 256, 0, stream>>>(x, pinv, pbeta, yp[0], yp[1], yp[2], wcat);

  k_conv3<<<dim3(N_ / 128, 3, B_), 256, 0, stream>>>(yp[0], yp[1], yp[2],
                                                     wb[0], wb[1], wb[2],
                                                     cbb[0], cbb[1], cbb[2], gamma,
                                                     fbuf, gbuf, hbuf);

  k_stats<<<576, 256, 0, stream>>>(fbuf, gbuf, pstats);
  k_stats_red<<<(B_ * N_ + 255) / 256, 256, 0, stream>>>(pstats, astat);
  k_attn_out<<<1152, 256, 0, stream>>>(fbuf, gbuf, hbuf, astat, spart, wcat);

  k_se<<<B_, 128, 0, stream>>>(wcat, secw, secb, seuw, seub, sebuf);

  k_final<<<(TOT_OUT / 2 + 255) / 256, 256, 0, stream>>>(x, spart, sebuf, out);
}

// Round 15
// 264.260 us; speedup vs baseline: 1.0063x; 1.0063x over previous
//
#include <hip/hip_runtime.h>
#include <hip/hip_bf16.h>

#define B_   8
#define C_   128
#define H_   96
#define W_   96
#define HP_  98            // padded H/W
#define HO_  48
#define N_   2304          // HO_*HO_
#define K_CONV 1152        // C_*9
#define PLANE_IN  9216     // H_*W_
#define TOT_OUT (B_*C_*N_)
#define LOG2E 1.4426950408889634f

typedef __attribute__((ext_vector_type(8))) short          s16x8;
typedef __attribute__((ext_vector_type(8))) unsigned short u16x8;
typedef __attribute__((ext_vector_type(4))) unsigned short u16x4;
typedef __attribute__((ext_vector_type(2))) unsigned short u16x2;
typedef __attribute__((ext_vector_type(4))) float          f32x4;

// XOR-swizzled byte offsets for bf16 LDS tiles, 16 B granules
#define SW(row, q)   (((row) << 6) + ((((q) ^ (((row) >> 1) & 3))) << 4))   // 64 B rows
#define SW8(row, q)  (((row) << 7) + ((((q) ^ ((row) & 7))) << 4))           // 128 B rows
#define SW16(row, q) (((row) << 8) + ((((q) ^ ((row) & 15))) << 4))          // 256 B rows

// native gfx950 transcendentals: v_exp_f32 = 2^x, v_log_f32 = log2(x)
__device__ __forceinline__ float fexp2(float x) { return __builtin_amdgcn_exp2f(x); }
__device__ __forceinline__ float flog2(float x) { return __builtin_amdgcn_logf(x); }

__device__ __forceinline__ ushort f2bf(float f) {
  __hip_bfloat16 h = __float2bfloat16(f);
  return *reinterpret_cast<ushort*>(&h);
}
__device__ __forceinline__ float bf2f(ushort u) {
  unsigned int v = ((unsigned int)u) << 16;
  return __builtin_bit_cast(float, v);
}

// ------- conv weights fp32 OIHW -> bf16 [co][(kh*3+kw)*128+ci], 3 branches --
// tail block (x == 576, y == 0) computes the BN inv/beta params.
__global__ __launch_bounds__(256) void k_prep_w(
    const float* __restrict__ w0, const float* __restrict__ w1, const float* __restrict__ w2,
    ushort* __restrict__ o0, ushort* __restrict__ o1, ushort* __restrict__ o2,
    const float* __restrict__ bw0, const float* __restrict__ bb0,
    const float* __restrict__ bm0, const float* __restrict__ bv0,
    const float* __restrict__ bw1, const float* __restrict__ bb1,
    const float* __restrict__ bm1, const float* __restrict__ bv1,
    const float* __restrict__ bw2, const float* __restrict__ bb2,
    const float* __restrict__ bm2, const float* __restrict__ bv2,
    float* __restrict__ pinv, float* __restrict__ pbeta) {
  int p = blockIdx.y;
  if (blockIdx.x == (C_ * K_CONV) / 256) {   // tail: BN param prep
    if (p == 0 && threadIdx.x < 128) {
      int c = threadIdx.x;
      const float* ws[3] = {bw0, bw1, bw2};
      const float* bs[3] = {bb0, bb1, bb2};
      const float* ms[3] = {bm0, bm1, bm2};
      const float* vs[3] = {bv0, bv1, bv2};
      #pragma unroll
      for (int pb = 0; pb < 3; ++pb) {
        float iv = ws[pb][c] / sqrtf(vs[pb][c] + 1e-5f);
        pinv[pb * 128 + c] = iv;
        pbeta[pb * 128 + c] = bs[pb][c] - ms[pb][c] * iv;
      }
    }
    return;
  }
  const float* w = (p == 0 ? w0 : p == 1 ? w1 : w2);
  ushort* wb = (p == 0 ? o0 : p == 1 ? o1 : o2);
  int id = blockIdx.x * 256 + threadIdx.x;
  int co = id / K_CONV, rem = id - co * K_CONV;
  int tap = rem >> 7, ci = rem & 127;
  wb[id] = f2bf(w[co * K_CONV + ci * 9 + tap]);
}

// ------- x -> 3x padded NHWC bf16 y (BN+ReLU fused) + x channel-sums --------
__global__ __launch_bounds__(256) void k_prep_y(const float* __restrict__ x,
                                                const float* __restrict__ pinv,
                                                const float* __restrict__ pbeta,
                                                ushort* __restrict__ y0,
                                                ushort* __restrict__ y1,
                                                ushort* __restrict__ y2,
                                                float* __restrict__ wcat) {
  const int h1 = blockIdx.x, b = blockIdx.y, t = threadIdx.x;
  ushort* ys[3] = {y0 + (size_t)b * HP_ * HP_ * C_,
                   y1 + (size_t)b * HP_ * HP_ * C_,
                   y2 + (size_t)b * HP_ * HP_ * C_};
  u16x8 zer = (u16x8)0;
  if (h1 == 0 || h1 == HP_ - 1) {
    for (int p = 0; p < 3; ++p)
      for (int g = t; g < HP_ * C_ / 8; g += 256)
        *(u16x8*)(ys[p] + (size_t)h1 * HP_ * C_ + g * 8) = zer;
    return;
  }
  __shared__ float xs[128][97];
  const int h = h1 - 1;
  const float* xb = x + (size_t)b * C_ * PLANE_IN + h * W_;
  for (int id = t; id < 128 * 24; id += 256) {
    int ci = id / 24, w4 = id - ci * 24;
    float4 v = *(const float4*)(xb + (size_t)ci * PLANE_IN + w4 * 4);
    xs[ci][w4 * 4 + 0] = v.x; xs[ci][w4 * 4 + 1] = v.y;
    xs[ci][w4 * 4 + 2] = v.z; xs[ci][w4 * 4 + 3] = v.w;
  }
  __syncthreads();
  if (t < 128) {               // x channel-sum for SE
    float s = 0.f;
    #pragma unroll
    for (int k = 0; k < 96; ++k) s += xs[t][k];
    atomicAdd(&wcat[b * 256 + t], s);
  }
  if (t >= 128 && t < 160) {
    int tt = t - 128;
    int side = tt >> 4, cg = tt & 15;
    for (int p = 0; p < 3; ++p)
      *(u16x8*)(ys[p] + ((size_t)h1 * HP_ + (side ? HP_ - 1 : 0)) * C_ + cg * 8) = zer;
  }
  for (int p = 0; p < 3; ++p) {
    const float* inv = pinv + p * 128;
    const float* bet = pbeta + p * 128;
    for (int g = t; g < 96 * 16; g += 256) {
      int wdx = g >> 4, cg = g & 15;
      u16x8 o;
      #pragma unroll
      for (int k = 0; k < 8; ++k) {
        int ci = cg * 8 + k;
        o[k] = f2bf(fmaxf(xs[ci][wdx] * inv[ci] + bet[ci], 0.f));
      }
      *(u16x8*)(ys[p] + ((size_t)h1 * HP_ + (wdx + 1)) * C_ + cg * 8) = o;
    }
  }
}

// ------- merged MFMA conv (3 branches): grid (18, 3, 8) ---------------------
// 128co x 128n tile, 4 waves each 64co x 64n (16 MFMA/iter/wave).
// As/Bs double-buffered 4 x 8 KB = 32 KB; pipelined, one barrier/iter.
// Output scales: br0 *log2e, br2 *gamma.
__global__ __launch_bounds__(256) void k_conv3(
    const ushort* __restrict__ y0, const ushort* __restrict__ y1, const ushort* __restrict__ y2,
    const ushort* __restrict__ w0, const ushort* __restrict__ w1, const ushort* __restrict__ w2,
    const float* __restrict__ bi0, const float* __restrict__ bi1, const float* __restrict__ bi2,
    const float* __restrict__ gammap,
    ushort* __restrict__ fo, ushort* __restrict__ go, ushort* __restrict__ ho) {
  __shared__ __align__(16) char smem[32768];
  // As dbuf at 0/8192 ; Bs dbuf at 16384/24576
  const int br = blockIdx.y, b = blockIdx.z, n0 = blockIdx.x * 128;
  const int t = threadIdx.x, l = t & 63, w = t >> 6;
  const ushort* yb = (br == 0 ? y0 : br == 1 ? y1 : y2) + (size_t)b * HP_ * HP_ * C_;
  const ushort* wb = (br == 0 ? w0 : br == 1 ? w1 : w2);
  const float* bias = (br == 0 ? bi0 : br == 1 ? bi1 : bi2);
  const float gm = (br == 2) ? gammap[0] : (br == 0 ? LOG2E : 1.f);
  const int pos0 = t >> 2, q4 = t & 3;
  const int ng0 = n0 + pos0,       oh0 = ng0 / HO_, ow0 = ng0 - oh0 * HO_;
  const int ng1 = n0 + pos0 + 64,  oh1 = ng1 / HO_, ow1 = ng1 - oh1 * HO_;
  const int mh = (w & 1) * 64, nh = (w >> 1) * 64;
  f32x4 acc[4][4];
  #pragma unroll
  for (int i = 0; i < 4; ++i)
    #pragma unroll
    for (int j = 0; j < 4; ++j) acc[i][j] = (f32x4)0.f;

  u16x8 sA0, sA1, sB0, sB1;
  auto LD = [&](int k0) {
    int tap = k0 >> 7, ci0 = k0 & 127;
    int kh = tap / 3, kw = tap - kh * 3;
    sA0 = *(const u16x8*)(wb + (size_t)pos0 * K_CONV + k0 + q4 * 8);
    sA1 = *(const u16x8*)(wb + (size_t)(pos0 + 64) * K_CONV + k0 + q4 * 8);
    sB0 = *(const u16x8*)(yb + ((size_t)(2 * oh0 + kh) * HP_ + 2 * ow0 + kw) * C_ + ci0 + q4 * 8);
    sB1 = *(const u16x8*)(yb + ((size_t)(2 * oh1 + kh) * HP_ + 2 * ow1 + kw) * C_ + ci0 + q4 * 8);
  };
  auto ST = [&](char* As, char* Bs) {
    *(u16x8*)(As + SW(pos0, q4)) = sA0;
    *(u16x8*)(As + SW(pos0 + 64, q4)) = sA1;
    *(u16x8*)(Bs + SW(pos0, q4)) = sB0;
    *(u16x8*)(Bs + SW(pos0 + 64, q4)) = sB1;
  };

  LD(0);
  ST(smem, smem + 16384);
  __syncthreads();
  for (int s = 0; s < 36; ++s) {
    char* Asc = smem + ((s & 1) << 13);
    char* Bsc = smem + 16384 + ((s & 1) << 13);
    if (s < 35) LD((s + 1) * 32);          // issue early (T14)
    s16x8 af[4], bf[4];
    #pragma unroll
    for (int i = 0; i < 4; ++i) {
      int r = mh + i * 16 + (l & 15);
      af[i] = *(const s16x8*)(Asc + SW(r, (l >> 4)));
    }
    #pragma unroll
    for (int j = 0; j < 4; ++j) {
      int r = nh + j * 16 + (l & 15);
      bf[j] = *(const s16x8*)(Bsc + SW(r, (l >> 4)));
    }
    __builtin_amdgcn_s_setprio(1);
    #pragma unroll
    for (int i = 0; i < 4; ++i)
      #pragma unroll
      for (int j = 0; j < 4; ++j)
        acc[i][j] = __builtin_amdgcn_mfma_f32_16x16x32_bf16(af[i], bf[j], acc[i][j], 0, 0, 0);
    __builtin_amdgcn_s_setprio(0);
    if (s < 35)
      ST(smem + (((s + 1) & 1) << 13), smem + 16384 + (((s + 1) & 1) << 13));
    __syncthreads();
  }

  if (br < 2) {  // out[b][n][c] via LDS bounce (br0 scaled by log2e)
    ushort* out = (br == 0) ? fo : go;
    ushort* tb = (ushort*)smem;  // [128 pos][128 co] = 32 KB
    #pragma unroll
    for (int i = 0; i < 4; ++i) {
      int co4 = mh + i * 16 + (l >> 4) * 4;
      float4 bi = *(const float4*)&bias[co4];
      float bia[4] = {bi.x, bi.y, bi.z, bi.w};
      #pragma unroll
      for (int j = 0; j < 4; ++j) {
        int pp = nh + j * 16 + (l & 15);
        #pragma unroll
        for (int r = 0; r < 4; ++r)
          tb[pp * 128 + co4 + r] = f2bf((acc[i][j][r] + bia[r]) * gm);
      }
    }
    __syncthreads();
    #pragma unroll
    for (int it = 0; it < 8; ++it) {
      int g = t + it * 256;
      int row = g >> 4, gg = g & 15;
      u16x8 d = *(const u16x8*)(tb + row * 128 + gg * 8);
      *(u16x8*)(out + ((size_t)b * N_ + n0 + row) * C_ + gg * 8) = d;
    }
  } else {       // out[b][c][n] via LDS bounce, gamma folded
    ushort* tb = (ushort*)smem;  // [128 co][128 pos] = 32 KB
    #pragma unroll
    for (int i = 0; i < 4; ++i) {
      int co4 = mh + i * 16 + (l >> 4) * 4;
      float4 bi = *(const float4*)&bias[co4];
      float bia[4] = {bi.x, bi.y, bi.z, bi.w};
      #pragma unroll
      for (int j = 0; j < 4; ++j) {
        int pp = nh + j * 16 + (l & 15);
        #pragma unroll
        for (int r = 0; r < 4; ++r)
          tb[(co4 + r) * 128 + pp] = f2bf((acc[i][j][r] + bia[r]) * gm);
      }
    }
    __syncthreads();
    #pragma unroll
    for (int it = 0; it < 8; ++it) {
      int g = t + it * 256;
      int co = g >> 4, off2 = (g & 15) * 8;
      u16x8 d = *(const u16x8*)(tb + co * 128 + off2);
      *(u16x8*)(ho + ((size_t)b * C_ + co) * N_ + n0 + off2) = d;
    }
  }
}

// ------- pass 1: partial row stats over m-chunk; grid 1152 (XCD swizzle) ----
// r13 proven version: 64 n-rows/block, gs dbuf, T14 split, one barrier/iter.
__global__ __launch_bounds__(256) void k_stats(const ushort* __restrict__ f,
                                               const ushort* __restrict__ g,
                                               float2* __restrict__ pstats) {
  __shared__ __align__(16) char smem[32768];   // gs double buffer 2 x 16 KB
  const int blk = blockIdx.x;
  const int b = blk & 7, t2 = blk >> 3;
  const int n0 = (t2 % 36) * 64, mz = t2 / 36;
  const int t = threadIdx.x, l = t & 63, w = t >> 6, lo = l & 15, quad = l >> 4;
  const ushort* fb = f + (size_t)b * N_ * C_;
  const ushort* gb = g + (size_t)b * N_ * C_;
  s16x8 af[4];
  #pragma unroll
  for (int ks = 0; ks < 4; ++ks)
    af[ks] = *(const s16x8*)(fb + (size_t)(n0 + w * 16 + lo) * C_ + (ks * 4 + quad) * 8);
  float mloc[4], lloc[4];
  #pragma unroll
  for (int r = 0; r < 4; ++r) { mloc[r] = -1e30f; lloc[r] = 0.f; }
  const int m_beg = mz * 576;

  u16x8 st[4];
  #pragma unroll
  for (int it = 0; it < 4; ++it) {
    int G = t + it * 256, row = G >> 4, g16 = G & 15;
    st[it] = *(const u16x8*)(gb + (size_t)(m_beg + row) * C_ + g16 * 8);
  }
  #pragma unroll
  for (int it = 0; it < 4; ++it) {
    int G = t + it * 256, row = G >> 4, g16 = G & 15;
    *(u16x8*)(smem + SW16(row, g16)) = st[it];
  }
  __syncthreads();

  #pragma unroll
  for (int i9 = 0; i9 < 9; ++i9) {
    char* gs = smem + ((i9 & 1) << 14);
    if (i9 < 8) {
      int m0n = m_beg + (i9 + 1) * 64;
      #pragma unroll
      for (int it = 0; it < 4; ++it) {
        int G = t + it * 256, row = G >> 4, g16 = G & 15;
        st[it] = *(const u16x8*)(gb + (size_t)(m0n + row) * C_ + g16 * 8);
      }
    }
    f32x4 acc[4];
    #pragma unroll
    for (int j = 0; j < 4; ++j) acc[j] = (f32x4)0.f;
    __builtin_amdgcn_s_setprio(1);
    #pragma unroll
    for (int ks = 0; ks < 4; ++ks)
      #pragma unroll
      for (int j = 0; j < 4; ++j) {
        s16x8 bf = *(const s16x8*)(gs + SW16(j * 16 + lo, ks * 4 + quad));
        acc[j] = __builtin_amdgcn_mfma_f32_16x16x32_bf16(af[ks], bf, acc[j], 0, 0, 0);
      }
    __builtin_amdgcn_s_setprio(0);
    #pragma unroll
    for (int r = 0; r < 4; ++r) {
      float vmax = fmaxf(fmaxf(acc[0][r], acc[1][r]), fmaxf(acc[2][r], acc[3][r]));
      float mn = fmaxf(mloc[r], vmax);
      lloc[r] = lloc[r] * fexp2(mloc[r] - mn) +
                fexp2(acc[0][r] - mn) + fexp2(acc[1][r] - mn) +
                fexp2(acc[2][r] - mn) + fexp2(acc[3][r] - mn);
      mloc[r] = mn;
    }
    if (i9 < 8) {
      char* gn = smem + (((i9 + 1) & 1) << 14);
      #pragma unroll
      for (int it = 0; it < 4; ++it) {
        int G = t + it * 256, row = G >> 4, g16 = G & 15;
        *(u16x8*)(gn + SW16(row, g16)) = st[it];
      }
    }
    __syncthreads();
  }
  #pragma unroll
  for (int r = 0; r < 4; ++r) {
    #pragma unroll
    for (int o = 1; o < 16; o <<= 1) {
      float mo = __shfl_xor(mloc[r], o, 64);
      float lo2 = __shfl_xor(lloc[r], o, 64);
      float mn = fmaxf(mloc[r], mo);
      lloc[r] = lloc[r] * fexp2(mloc[r] - mn) + lo2 * fexp2(mo - mn);
      mloc[r] = mn;
    }
  }
  if (lo == 0) {
    #pragma unroll
    for (int r = 0; r < 4; ++r)
      pstats[((size_t)mz * B_ + b) * N_ + n0 + w * 16 + quad * 4 + r] =
          make_float2(mloc[r], lloc[r]);
  }
}

// ------- merge 4 partial stats -> a[n] = -mx2 - log2(l2)  (exp2 domain) -----
__global__ __launch_bounds__(256) void k_stats_red(const float2* __restrict__ p,
                                                   float* __restrict__ astat) {
  int idx = blockIdx.x * 256 + threadIdx.x;   // b*N+n
  if (idx >= B_ * N_) return;
  float mx = -1e30f, ls = 0.f;
  #pragma unroll
  for (int z = 0; z < 4; ++z) {
    float2 s = p[(size_t)z * B_ * N_ + idx];
    float mn = fmaxf(mx, s.x);
    ls = ls * fexp2(mx - mn) + s.y * fexp2(s.x - mn);
    mx = mn;
  }
  astat[idx] = -mx - flog2(ls);
}

// ------- pass 2: fused scores+softmax+PV partials; grid 1152 (XCD swizzle) --
// v9: spart stored as bf16 (halves write traffic; 2.0 abs tolerance).
// s-row sums computed from f32 values inside the ss-bounce loop.
__global__ __launch_bounds__(256) void k_attn_out(const ushort* __restrict__ f,
                                                  const ushort* __restrict__ g,
                                                  const ushort* __restrict__ h,
                                                  const float* __restrict__ astat,
                                                  ushort* __restrict__ spart,
                                                  float* __restrict__ wcat) {
  __shared__ __align__(16) char smem[32768];
  char* gs = smem;            // [64 m][128 c] SW16 16 KB (staged once)
  char* pTb = smem + 16384;   // pT double buffer 2 x 8 KB
  const int blk = blockIdx.x;
  const int b = blk & 7, t2 = blk >> 3;
  const int m0 = (t2 % 36) * 64, nz = t2 / 36;
  const int t = threadIdx.x, l = t & 63, w = t >> 6, lo = l & 15, quad = l >> 4;
  const ushort* fb = f + (size_t)b * N_ * C_;
  const ushort* gb = g + (size_t)b * N_ * C_;
  const ushort* hb = h + (size_t)b * C_ * N_;
  const float* ab = astat + (size_t)b * N_;
  #pragma unroll
  for (int it = 0; it < 4; ++it) {   // gs: 1024 granules, once
    int G = t + it * 256, row = G >> 4, g16 = G & 15;
    *(u16x8*)(gs + SW16(row, g16)) = *(const u16x8*)(gb + (size_t)(m0 + row) * C_ + g16 * 8);
  }
  f32x4 accs[2][4];
  #pragma unroll
  for (int i = 0; i < 2; ++i)
    #pragma unroll
    for (int j = 0; j < 4; ++j) accs[i][j] = (f32x4)0.f;
  const int n_beg = nz * 576;

  s16x8 af[2][4];
  s16x8 ahc[2][2];
  float ax[2][4];

  auto LOAD_AF = [&](int i, int p) {
    int nb = n_beg + i * 64;
    #pragma unroll
    for (int ks = 0; ks < 4; ++ks)
      af[p][ks] = *(const s16x8*)(fb + (size_t)(nb + w * 16 + lo) * C_ + (ks * 4 + quad) * 8);
    float4 av = *(const float4*)(ab + nb + w * 16 + quad * 4);
    ax[p][0] = av.x; ax[p][1] = av.y; ax[p][2] = av.z; ax[p][3] = av.w;
  };
  auto LOAD_AH = [&](int i) {
    int nb = n_beg + i * 64;
    #pragma unroll
    for (int ii = 0; ii < 2; ++ii)
      #pragma unroll
      for (int ks = 0; ks < 2; ++ks)
        ahc[ii][ks] = *(const s16x8*)(hb + (size_t)((2 * w + ii) * 16 + lo) * N_ + nb + (ks * 4 + quad) * 8);
  };
  auto QKEXP = [&](int p) {
    char* pT = pTb + (p << 13);
    f32x4 sc[4];
    #pragma unroll
    for (int j = 0; j < 4; ++j) sc[j] = (f32x4)0.f;
    __builtin_amdgcn_s_setprio(1);
    #pragma unroll
    for (int ks = 0; ks < 4; ++ks)
      #pragma unroll
      for (int j = 0; j < 4; ++j) {
        s16x8 bg = *(const s16x8*)(gs + SW16(j * 16 + lo, ks * 4 + quad));
        sc[j] = __builtin_amdgcn_mfma_f32_16x16x32_bf16(af[p][ks], bg, sc[j], 0, 0, 0);
      }
    __builtin_amdgcn_s_setprio(0);
    const int nl = w * 16 + quad * 4;
    #pragma unroll
    for (int j = 0; j < 4; ++j) {
      u16x4 pv;
      #pragma unroll
      for (int r = 0; r < 4; ++r)
        pv[r] = f2bf(fexp2(sc[j][r] + ax[p][r]));
      *(u16x4*)(pT + SW8(j * 16 + lo, nl >> 3) + (nl & 7) * 2) = pv;
    }
  };
  auto PV = [&](int p) {
    char* pT = pTb + (p << 13);
    __builtin_amdgcn_s_setprio(1);
    #pragma unroll
    for (int ks = 0; ks < 2; ++ks)
      #pragma unroll
      for (int j = 0; j < 4; ++j) {
        s16x8 bp = *(const s16x8*)(pT + SW8(j * 16 + lo, ks * 4 + quad));
        accs[0][j] = __builtin_amdgcn_mfma_f32_16x16x32_bf16(ahc[0][ks], bp, accs[0][j], 0, 0, 0);
        accs[1][j] = __builtin_amdgcn_mfma_f32_16x16x32_bf16(ahc[1][ks], bp, accs[1][j], 0, 0, 0);
      }
    __builtin_amdgcn_s_setprio(0);
  };

  LOAD_AF(0, 0);
  LOAD_AH(0);
  __syncthreads();           // gs staged
  QKEXP(0);                  // writes pT[0]
  LOAD_AF(1, 1);
  #pragma unroll
  for (int i9 = 0; i9 < 9; ++i9) {
    __syncthreads();         // pT[i9&1] published
    PV(i9 & 1);
    if (i9 < 8) {
      LOAD_AH(i9 + 1);
      QKEXP((i9 + 1) & 1);
      if (i9 < 7) LOAD_AF(i9 + 2, i9 & 1);
    }
  }
  // epilogue: two-chunk f32 transpose bounce -> bf16 stores (128 B segments).
  // s-row sums from the f32 values (16 consecutive lanes share ci).
  ushort* outp = spart + (size_t)nz * TOT_OUT + (size_t)b * C_ * N_ + m0;
  float* ss = (float*)smem;   // [64 rows][68] f32 = 17408 B (gs/pT dead)
  #pragma unroll
  for (int ch = 0; ch < 2; ++ch) {
    __syncthreads();          // pT reads done / prior chunk stores done
    {
      int ci0 = w * 16 + quad * 4;
      #pragma unroll
      for (int j = 0; j < 4; ++j) {
        int m = j * 16 + lo;
        #pragma unroll
        for (int r = 0; r < 4; ++r)
          ss[(ci0 + r) * 68 + m] = accs[ch][j][r];
      }
    }
    __syncthreads();
    #pragma unroll
    for (int it = 0; it < 4; ++it) {
      int idx = t + it * 256;
      int ci = idx >> 4, mq = idx & 15;
      int c = (ci >> 4) * 32 + ch * 16 + (ci & 15);
      float4 v = *(const float4*)&ss[ci * 68 + mq * 4];
      u16x4 pv;
      pv[0] = f2bf(v.x); pv[1] = f2bf(v.y); pv[2] = f2bf(v.z); pv[3] = f2bf(v.w);
      *(u16x4*)&outp[(size_t)c * N_ + mq * 4] = pv;
      float sm = (v.x + v.y) + (v.z + v.w);
      #pragma unroll
      for (int o = 1; o < 16; o <<= 1) sm += __shfl_xor(sm, o, 64);
      if (mq == 0) atomicAdd(&wcat[(b << 8) + 128 + c], sm);
    }
  }
}

// ---------------- SE MLP: 256 -> 42 (relu) -> 128 ---------------------------
// wcat holds RAW sums both halves: x-sums (prep_y) and s-sums (attn epilogue).
__global__ __launch_bounds__(128) void k_se(const float* __restrict__ wcat,
                                            const float* __restrict__ cw,
                                            const float* __restrict__ cb,
                                            const float* __restrict__ uw,
                                            const float* __restrict__ ub,
                                            float* __restrict__ se) {
  const int b = blockIdx.x, t = threadIdx.x;
  __shared__ float wc[256];
  __shared__ float s1[42];
  wc[t] = fmaxf(wcat[b * 256 + t] * (1.f / PLANE_IN), 0.f);
  wc[128 + t] = fmaxf(wcat[b * 256 + 128 + t] * (1.f / N_), 0.f);
  __syncthreads();
  if (t < 42) {
    float a = cb[t];
    const float* r = cw + (size_t)t * 256;
    for (int k = 0; k < 256; ++k) a += wc[k] * r[k];
    s1[t] = fmaxf(a, 0.f);
  }
  __syncthreads();
  {
    float a = ub[t];
    const float* r = uw + (size_t)t * 42;
    for (int j = 0; j < 42; ++j) a += s1[j] * r[j];
    se[b * 128 + t] = a;
  }
}

// ------- out = (avgpool2x2(x) + sum_z spart_bf16[z]) * (1 + se) -------------
__global__ __launch_bounds__(256) void k_final(const float* __restrict__ x,
                                               const ushort* __restrict__ spart,
                                               const float* __restrict__ se,
                                               float* __restrict__ out) {
  int idx = blockIdx.x * 256 + threadIdx.x;
  if (idx >= TOT_OUT / 2) return;
  int m2 = idx % (N_ / 2);
  int bc = idx / (N_ / 2);
  int oh = m2 / (HO_ / 2), owp = m2 - oh * (HO_ / 2);
  size_t base = (size_t)bc * N_ + oh * HO_ + owp * 2;
  const float* xp = x + (size_t)bc * PLANE_IN;
  int ih = oh * 2, iw = owp * 4;
  float4 a = *(const float4*)(xp + ih * W_ + iw);
  float4 bb = *(const float4*)(xp + (ih + 1) * W_ + iw);
  float l0 = 0.25f * (a.x + a.y + bb.x + bb.y);
  float l1 = 0.25f * (a.z + a.w + bb.z + bb.w);
  u16x2 s0 = *(const u16x2*)(spart + base);
  u16x2 s1 = *(const u16x2*)(spart + (size_t)TOT_OUT + base);
  u16x2 s2 = *(const u16x2*)(spart + 2 * (size_t)TOT_OUT + base);
  u16x2 s3 = *(const u16x2*)(spart + 3 * (size_t)TOT_OUT + base);
  float sc = 1.f + se[bc];
  float2 o;
  o.x = (l0 + bf2f(s0[0]) + bf2f(s1[0]) + bf2f(s2[0]) + bf2f(s3[0])) * sc;
  o.y = (l1 + bf2f(s0[1]) + bf2f(s1[1]) + bf2f(s2[1]) + bf2f(s3[1])) * sc;
  *(float2*)(out + base) = o;
}

extern "C" void kernel_launch(void* const* d_in, const int* in_sizes, int n_in,
                              void* d_out, int out_size, void* d_ws, size_t ws_size,
                              hipStream_t stream) {
  (void)in_sizes; (void)n_in; (void)out_size; (void)ws_size;
  const float* x    = (const float*)d_in[0];
  const float* bnw[3] = {(const float*)d_in[1],  (const float*)d_in[7],  (const float*)d_in[13]};
  const float* bnb[3] = {(const float*)d_in[2],  (const float*)d_in[8],  (const float*)d_in[14]};
  const float* bnm[3] = {(const float*)d_in[3],  (const float*)d_in[9],  (const float*)d_in[15]};
  const float* bnv[3] = {(const float*)d_in[4],  (const float*)d_in[10], (const float*)d_in[16]};
  const float* cw_[3] = {(const float*)d_in[5],  (const float*)d_in[11], (const float*)d_in[17]};
  const float* cbb[3] = {(const float*)d_in[6],  (const float*)d_in[12], (const float*)d_in[18]};
  const float* secw = (const float*)d_in[19];
  const float* secb = (const float*)d_in[20];
  const float* seuw = (const float*)d_in[21];
  const float* seub = (const float*)d_in[22];
  const float* gamma = (const float*)d_in[23];
  float* out = (float*)d_out;

  char* ws = (char*)d_ws;
  size_t off = 0;
  auto alloc = [&](size_t bytes) -> char* {
    char* p = ws + off;
    off = (off + bytes + 255) & ~(size_t)255;
    return p;
  };
  ushort* yp[3];
  for (int p = 0; p < 3; ++p) yp[p] = (ushort*)alloc((size_t)B_ * HP_ * HP_ * C_ * 2);
  ushort* wb[3];
  for (int p = 0; p < 3; ++p) wb[p] = (ushort*)alloc((size_t)C_ * K_CONV * 2);
  ushort* fbuf = (ushort*)alloc((size_t)B_ * N_ * C_ * 2);       // [b][n][c], *log2e
  ushort* gbuf = (ushort*)alloc((size_t)B_ * N_ * C_ * 2);       // [b][n][c]
  ushort* hbuf = (ushort*)alloc((size_t)B_ * C_ * N_ * 2);       // [b][c][n], *gamma
  float2* pstats = (float2*)alloc((size_t)4 * B_ * N_ * 8);      // partial (mx2,l2)
  float*  astat  = (float*)alloc((size_t)B_ * N_ * 4);           // -mx2 - log2(l2)
  ushort* spart = (ushort*)alloc((size_t)4 * TOT_OUT * 2);       // partial PV sums (bf16)
  float*  wcat = (float*)alloc(B_ * 256 * 4);
  float*  sebuf = (float*)alloc(B_ * 128 * 4);
  float*  pinv  = (float*)alloc(3 * 128 * 4);
  float*  pbeta = (float*)alloc(3 * 128 * 4);

  hipMemsetAsync(wcat, 0, B_ * 256 * 4, stream);   // raw-sum accumulators

  k_prep_w<<<dim3((C_ * K_CONV) / 256 + 1, 3), 256, 0, stream>>>(
      cw_[0], cw_[1], cw_[2], wb[0], wb[1], wb[2],
      bnw[0], bnb[0], bnm[0], bnv[0],
      bnw[1], bnb[1], bnm[1], bnv[1],
      bnw[2], bnb[2], bnm[2], bnv[2], pinv, pbeta);
  k_prep_y<<<dim3(HP_, B_), 256, 0, stream>>>(x, pinv, pbeta, yp[0], yp[1], yp[2], wcat);

  k_conv3<<<dim3(N_ / 128, 3, B_), 256, 0, stream>>>(yp[0], yp[1], yp[2],
                                                     wb[0], wb[1], wb[2],
                                                     cbb[0], cbb[1], cbb[2], gamma,
                                                     fbuf, gbuf, hbuf);

  k_stats<<<1152, 256, 0, stream>>>(fbuf, gbuf, pstats);
  k_stats_red<<<(B_ * N_ + 255) / 256, 256, 0, stream>>>(pstats, astat);
  k_attn_out<<<1152, 256, 0, stream>>>(fbuf, gbuf, hbuf, astat, spart, wcat);

  k_se<<<B_, 128, 0, stream>>>(wcat, secw, secb, seuw, seub, sebuf);

  k_final<<<(TOT_OUT / 2 + 255) / 256, 256, 0, stream>>>(x, spart, sebuf, out);
}

// Round 16
// 259.691 us; speedup vs baseline: 1.0240x; 1.0176x over previous
//
#include <hip/hip_runtime.h>
#include <hip/hip_bf16.h>

#define B_   8
#define C_   128
#define H_   96
#define W_   96
#define HP_  98            // padded H/W
#define HO_  48
#define N_   2304          // HO_*HO_
#define K_CONV 1152        // C_*9
#define PLANE_IN  9216     // H_*W_
#define TOT_OUT (B_*C_*N_)
#define LOG2E 1.4426950408889634f

typedef __attribute__((ext_vector_type(8))) short          s16x8;
typedef __attribute__((ext_vector_type(8))) unsigned short u16x8;
typedef __attribute__((ext_vector_type(4))) unsigned short u16x4;
typedef __attribute__((ext_vector_type(2))) unsigned short u16x2;
typedef __attribute__((ext_vector_type(4))) float          f32x4;

// XOR-swizzled byte offsets for bf16 LDS tiles, 16 B granules
#define SW(row, q)   (((row) << 6) + ((((q) ^ (((row) >> 1) & 3))) << 4))   // 64 B rows
#define SW8(row, q)  (((row) << 7) + ((((q) ^ ((row) & 7))) << 4))           // 128 B rows
#define SW16(row, q) (((row) << 8) + ((((q) ^ ((row) & 15))) << 4))          // 256 B rows

// native gfx950 transcendentals: v_exp_f32 = 2^x, v_log_f32 = log2(x)
__device__ __forceinline__ float fexp2(float x) { return __builtin_amdgcn_exp2f(x); }
__device__ __forceinline__ float flog2(float x) { return __builtin_amdgcn_logf(x); }

// Barrier that drains ONLY LDS ops (lgkmcnt) -- prefetched global loads stay
// in flight across it (plain __syncthreads emits s_waitcnt vmcnt(0) too,
// stalling every iteration on prefetch completion). "memory" clobber keeps
// ds ops from crossing; compiler still inserts vmcnt waits at load consumers.
__device__ __forceinline__ void bar_lgkm() {
  asm volatile("s_waitcnt lgkmcnt(0)" ::: "memory");
  __builtin_amdgcn_s_barrier();
}

__device__ __forceinline__ ushort f2bf(float f) {
  __hip_bfloat16 h = __float2bfloat16(f);
  return *reinterpret_cast<ushort*>(&h);
}
__device__ __forceinline__ float bf2f(ushort u) {
  unsigned int v = ((unsigned int)u) << 16;
  return __builtin_bit_cast(float, v);
}

// ------- conv weights fp32 OIHW -> bf16 [co][(kh*3+kw)*128+ci], 3 branches --
// tail block (x == 576, y == 0) computes the BN inv/beta params.
__global__ __launch_bounds__(256) void k_prep_w(
    const float* __restrict__ w0, const float* __restrict__ w1, const float* __restrict__ w2,
    ushort* __restrict__ o0, ushort* __restrict__ o1, ushort* __restrict__ o2,
    const float* __restrict__ bw0, const float* __restrict__ bb0,
    const float* __restrict__ bm0, const float* __restrict__ bv0,
    const float* __restrict__ bw1, const float* __restrict__ bb1,
    const float* __restrict__ bm1, const float* __restrict__ bv1,
    const float* __restrict__ bw2, const float* __restrict__ bb2,
    const float* __restrict__ bm2, const float* __restrict__ bv2,
    float* __restrict__ pinv, float* __restrict__ pbeta) {
  int p = blockIdx.y;
  if (blockIdx.x == (C_ * K_CONV) / 256) {   // tail: BN param prep
    if (p == 0 && threadIdx.x < 128) {
      int c = threadIdx.x;
      const float* ws[3] = {bw0, bw1, bw2};
      const float* bs[3] = {bb0, bb1, bb2};
      const float* ms[3] = {bm0, bm1, bm2};
      const float* vs[3] = {bv0, bv1, bv2};
      #pragma unroll
      for (int pb = 0; pb < 3; ++pb) {
        float iv = ws[pb][c] / sqrtf(vs[pb][c] + 1e-5f);
        pinv[pb * 128 + c] = iv;
        pbeta[pb * 128 + c] = bs[pb][c] - ms[pb][c] * iv;
      }
    }
    return;
  }
  const float* w = (p == 0 ? w0 : p == 1 ? w1 : w2);
  ushort* wb = (p == 0 ? o0 : p == 1 ? o1 : o2);
  int id = blockIdx.x * 256 + threadIdx.x;
  int co = id / K_CONV, rem = id - co * K_CONV;
  int tap = rem >> 7, ci = rem & 127;
  wb[id] = f2bf(w[co * K_CONV + ci * 9 + tap]);
}

// ------- x -> 3x padded NHWC bf16 y (BN+ReLU fused) + x channel-sums --------
__global__ __launch_bounds__(256) void k_prep_y(const float* __restrict__ x,
                                                const float* __restrict__ pinv,
                                                const float* __restrict__ pbeta,
                                                ushort* __restrict__ y0,
                                                ushort* __restrict__ y1,
                                                ushort* __restrict__ y2,
                                                float* __restrict__ wcat) {
  const int h1 = blockIdx.x, b = blockIdx.y, t = threadIdx.x;
  ushort* ys[3] = {y0 + (size_t)b * HP_ * HP_ * C_,
                   y1 + (size_t)b * HP_ * HP_ * C_,
                   y2 + (size_t)b * HP_ * HP_ * C_};
  u16x8 zer = (u16x8)0;
  if (h1 == 0 || h1 == HP_ - 1) {
    for (int p = 0; p < 3; ++p)
      for (int g = t; g < HP_ * C_ / 8; g += 256)
        *(u16x8*)(ys[p] + (size_t)h1 * HP_ * C_ + g * 8) = zer;
    return;
  }
  __shared__ float xs[128][97];
  const int h = h1 - 1;
  const float* xb = x + (size_t)b * C_ * PLANE_IN + h * W_;
  for (int id = t; id < 128 * 24; id += 256) {
    int ci = id / 24, w4 = id - ci * 24;
    float4 v = *(const float4*)(xb + (size_t)ci * PLANE_IN + w4 * 4);
    xs[ci][w4 * 4 + 0] = v.x; xs[ci][w4 * 4 + 1] = v.y;
    xs[ci][w4 * 4 + 2] = v.z; xs[ci][w4 * 4 + 3] = v.w;
  }
  __syncthreads();
  if (t < 128) {               // x channel-sum for SE
    float s = 0.f;
    #pragma unroll
    for (int k = 0; k < 96; ++k) s += xs[t][k];
    atomicAdd(&wcat[b * 256 + t], s);
  }
  if (t >= 128 && t < 160) {
    int tt = t - 128;
    int side = tt >> 4, cg = tt & 15;
    for (int p = 0; p < 3; ++p)
      *(u16x8*)(ys[p] + ((size_t)h1 * HP_ + (side ? HP_ - 1 : 0)) * C_ + cg * 8) = zer;
  }
  for (int p = 0; p < 3; ++p) {
    const float* inv = pinv + p * 128;
    const float* bet = pbeta + p * 128;
    for (int g = t; g < 96 * 16; g += 256) {
      int wdx = g >> 4, cg = g & 15;
      u16x8 o;
      #pragma unroll
      for (int k = 0; k < 8; ++k) {
        int ci = cg * 8 + k;
        o[k] = f2bf(fmaxf(xs[ci][wdx] * inv[ci] + bet[ci], 0.f));
      }
      *(u16x8*)(ys[p] + ((size_t)h1 * HP_ + (wdx + 1)) * C_ + cg * 8) = o;
    }
  }
}

// ------- merged MFMA conv (3 branches): grid (18, 3, 8) ---------------------
// 128co x 128n tile, 4 waves each 64co x 64n (16 MFMA/iter/wave).
// As/Bs double-buffered 4 x 8 KB = 32 KB; pipelined, one lgkm-barrier/iter
// (VMEM prefetch rides across). Output scales: br0 *log2e, br2 *gamma.
__global__ __launch_bounds__(256) void k_conv3(
    const ushort* __restrict__ y0, const ushort* __restrict__ y1, const ushort* __restrict__ y2,
    const ushort* __restrict__ w0, const ushort* __restrict__ w1, const ushort* __restrict__ w2,
    const float* __restrict__ bi0, const float* __restrict__ bi1, const float* __restrict__ bi2,
    const float* __restrict__ gammap,
    ushort* __restrict__ fo, ushort* __restrict__ go, ushort* __restrict__ ho) {
  __shared__ __align__(16) char smem[32768];
  const int br = blockIdx.y, b = blockIdx.z, n0 = blockIdx.x * 128;
  const int t = threadIdx.x, l = t & 63, w = t >> 6;
  const ushort* yb = (br == 0 ? y0 : br == 1 ? y1 : y2) + (size_t)b * HP_ * HP_ * C_;
  const ushort* wb = (br == 0 ? w0 : br == 1 ? w1 : w2);
  const float* bias = (br == 0 ? bi0 : br == 1 ? bi1 : bi2);
  const float gm = (br == 2) ? gammap[0] : (br == 0 ? LOG2E : 1.f);
  const int pos0 = t >> 2, q4 = t & 3;
  const int ng0 = n0 + pos0,       oh0 = ng0 / HO_, ow0 = ng0 - oh0 * HO_;
  const int ng1 = n0 + pos0 + 64,  oh1 = ng1 / HO_, ow1 = ng1 - oh1 * HO_;
  const int mh = (w & 1) * 64, nh = (w >> 1) * 64;
  f32x4 acc[4][4];
  #pragma unroll
  for (int i = 0; i < 4; ++i)
    #pragma unroll
    for (int j = 0; j < 4; ++j) acc[i][j] = (f32x4)0.f;

  u16x8 sA0, sA1, sB0, sB1;
  auto LD = [&](int k0) {
    int tap = k0 >> 7, ci0 = k0 & 127;
    int kh = tap / 3, kw = tap - kh * 3;
    sA0 = *(const u16x8*)(wb + (size_t)pos0 * K_CONV + k0 + q4 * 8);
    sA1 = *(const u16x8*)(wb + (size_t)(pos0 + 64) * K_CONV + k0 + q4 * 8);
    sB0 = *(const u16x8*)(yb + ((size_t)(2 * oh0 + kh) * HP_ + 2 * ow0 + kw) * C_ + ci0 + q4 * 8);
    sB1 = *(const u16x8*)(yb + ((size_t)(2 * oh1 + kh) * HP_ + 2 * ow1 + kw) * C_ + ci0 + q4 * 8);
  };
  auto ST = [&](char* As, char* Bs) {
    *(u16x8*)(As + SW(pos0, q4)) = sA0;
    *(u16x8*)(As + SW(pos0 + 64, q4)) = sA1;
    *(u16x8*)(Bs + SW(pos0, q4)) = sB0;
    *(u16x8*)(Bs + SW(pos0 + 64, q4)) = sB1;
  };

  LD(0);
  ST(smem, smem + 16384);
  bar_lgkm();
  for (int s = 0; s < 36; ++s) {
    char* Asc = smem + ((s & 1) << 13);
    char* Bsc = smem + 16384 + ((s & 1) << 13);
    if (s < 35) LD((s + 1) * 32);          // issue early (T14)
    s16x8 af[4], bf[4];
    #pragma unroll
    for (int i = 0; i < 4; ++i) {
      int r = mh + i * 16 + (l & 15);
      af[i] = *(const s16x8*)(Asc + SW(r, (l >> 4)));
    }
    #pragma unroll
    for (int j = 0; j < 4; ++j) {
      int r = nh + j * 16 + (l & 15);
      bf[j] = *(const s16x8*)(Bsc + SW(r, (l >> 4)));
    }
    __builtin_amdgcn_s_setprio(1);
    #pragma unroll
    for (int i = 0; i < 4; ++i)
      #pragma unroll
      for (int j = 0; j < 4; ++j)
        acc[i][j] = __builtin_amdgcn_mfma_f32_16x16x32_bf16(af[i], bf[j], acc[i][j], 0, 0, 0);
    __builtin_amdgcn_s_setprio(0);
    if (s < 35)
      ST(smem + (((s + 1) & 1) << 13), smem + 16384 + (((s + 1) & 1) << 13));
    bar_lgkm();
  }

  if (br < 2) {  // out[b][n][c] via LDS bounce (br0 scaled by log2e)
    ushort* out = (br == 0) ? fo : go;
    ushort* tb = (ushort*)smem;  // [128 pos][128 co] = 32 KB
    #pragma unroll
    for (int i = 0; i < 4; ++i) {
      int co4 = mh + i * 16 + (l >> 4) * 4;
      float4 bi = *(const float4*)&bias[co4];
      float bia[4] = {bi.x, bi.y, bi.z, bi.w};
      #pragma unroll
      for (int j = 0; j < 4; ++j) {
        int pp = nh + j * 16 + (l & 15);
        #pragma unroll
        for (int r = 0; r < 4; ++r)
          tb[pp * 128 + co4 + r] = f2bf((acc[i][j][r] + bia[r]) * gm);
      }
    }
    bar_lgkm();
    #pragma unroll
    for (int it = 0; it < 8; ++it) {
      int g = t + it * 256;
      int row = g >> 4, gg = g & 15;
      u16x8 d = *(const u16x8*)(tb + row * 128 + gg * 8);
      *(u16x8*)(out + ((size_t)b * N_ + n0 + row) * C_ + gg * 8) = d;
    }
  } else {       // out[b][c][n] via LDS bounce, gamma folded
    ushort* tb = (ushort*)smem;  // [128 co][128 pos] = 32 KB
    #pragma unroll
    for (int i = 0; i < 4; ++i) {
      int co4 = mh + i * 16 + (l >> 4) * 4;
      float4 bi = *(const float4*)&bias[co4];
      float bia[4] = {bi.x, bi.y, bi.z, bi.w};
      #pragma unroll
      for (int j = 0; j < 4; ++j) {
        int pp = nh + j * 16 + (l & 15);
        #pragma unroll
        for (int r = 0; r < 4; ++r)
          tb[(co4 + r) * 128 + pp] = f2bf((acc[i][j][r] + bia[r]) * gm);
      }
    }
    bar_lgkm();
    #pragma unroll
    for (int it = 0; it < 8; ++it) {
      int g = t + it * 256;
      int co = g >> 4, off2 = (g & 15) * 8;
      u16x8 d = *(const u16x8*)(tb + co * 128 + off2);
      *(u16x8*)(ho + ((size_t)b * C_ + co) * N_ + n0 + off2) = d;
    }
  }
}

// ------- pass 1: partial row stats over m-chunk; grid 1152 (XCD swizzle) ----
// 64 n-rows/block, gs dbuf, T14 split, one lgkm-barrier/iter.
__global__ __launch_bounds__(256) void k_stats(const ushort* __restrict__ f,
                                               const ushort* __restrict__ g,
                                               float2* __restrict__ pstats) {
  __shared__ __align__(16) char smem[32768];   // gs double buffer 2 x 16 KB
  const int blk = blockIdx.x;
  const int b = blk & 7, t2 = blk >> 3;
  const int n0 = (t2 % 36) * 64, mz = t2 / 36;
  const int t = threadIdx.x, l = t & 63, w = t >> 6, lo = l & 15, quad = l >> 4;
  const ushort* fb = f + (size_t)b * N_ * C_;
  const ushort* gb = g + (size_t)b * N_ * C_;
  s16x8 af[4];
  #pragma unroll
  for (int ks = 0; ks < 4; ++ks)
    af[ks] = *(const s16x8*)(fb + (size_t)(n0 + w * 16 + lo) * C_ + (ks * 4 + quad) * 8);
  float mloc[4], lloc[4];
  #pragma unroll
  for (int r = 0; r < 4; ++r) { mloc[r] = -1e30f; lloc[r] = 0.f; }
  const int m_beg = mz * 576;

  u16x8 st[4];
  #pragma unroll
  for (int it = 0; it < 4; ++it) {
    int G = t + it * 256, row = G >> 4, g16 = G & 15;
    st[it] = *(const u16x8*)(gb + (size_t)(m_beg + row) * C_ + g16 * 8);
  }
  #pragma unroll
  for (int it = 0; it < 4; ++it) {
    int G = t + it * 256, row = G >> 4, g16 = G & 15;
    *(u16x8*)(smem + SW16(row, g16)) = st[it];
  }
  bar_lgkm();

  #pragma unroll
  for (int i9 = 0; i9 < 9; ++i9) {
    char* gs = smem + ((i9 & 1) << 14);
    if (i9 < 8) {
      int m0n = m_beg + (i9 + 1) * 64;
      #pragma unroll
      for (int it = 0; it < 4; ++it) {
        int G = t + it * 256, row = G >> 4, g16 = G & 15;
        st[it] = *(const u16x8*)(gb + (size_t)(m0n + row) * C_ + g16 * 8);
      }
    }
    f32x4 acc[4];
    #pragma unroll
    for (int j = 0; j < 4; ++j) acc[j] = (f32x4)0.f;
    __builtin_amdgcn_s_setprio(1);
    #pragma unroll
    for (int ks = 0; ks < 4; ++ks)
      #pragma unroll
      for (int j = 0; j < 4; ++j) {
        s16x8 bf = *(const s16x8*)(gs + SW16(j * 16 + lo, ks * 4 + quad));
        acc[j] = __builtin_amdgcn_mfma_f32_16x16x32_bf16(af[ks], bf, acc[j], 0, 0, 0);
      }
    __builtin_amdgcn_s_setprio(0);
    #pragma unroll
    for (int r = 0; r < 4; ++r) {
      float vmax = fmaxf(fmaxf(acc[0][r], acc[1][r]), fmaxf(acc[2][r], acc[3][r]));
      float mn = fmaxf(mloc[r], vmax);
      lloc[r] = lloc[r] * fexp2(mloc[r] - mn) +
                fexp2(acc[0][r] - mn) + fexp2(acc[1][r] - mn) +
                fexp2(acc[2][r] - mn) + fexp2(acc[3][r] - mn);
      mloc[r] = mn;
    }
    if (i9 < 8) {
      char* gn = smem + (((i9 + 1) & 1) << 14);
      #pragma unroll
      for (int it = 0; it < 4; ++it) {
        int G = t + it * 256, row = G >> 4, g16 = G & 15;
        *(u16x8*)(gn + SW16(row, g16)) = st[it];
      }
    }
    bar_lgkm();
  }
  #pragma unroll
  for (int r = 0; r < 4; ++r) {
    #pragma unroll
    for (int o = 1; o < 16; o <<= 1) {
      float mo = __shfl_xor(mloc[r], o, 64);
      float lo2 = __shfl_xor(lloc[r], o, 64);
      float mn = fmaxf(mloc[r], mo);
      lloc[r] = lloc[r] * fexp2(mloc[r] - mn) + lo2 * fexp2(mo - mn);
      mloc[r] = mn;
    }
  }
  if (lo == 0) {
    #pragma unroll
    for (int r = 0; r < 4; ++r)
      pstats[((size_t)mz * B_ + b) * N_ + n0 + w * 16 + quad * 4 + r] =
          make_float2(mloc[r], lloc[r]);
  }
}

// ------- merge 4 partial stats -> a[n] = -mx2 - log2(l2)  (exp2 domain) -----
__global__ __launch_bounds__(256) void k_stats_red(const float2* __restrict__ p,
                                                   float* __restrict__ astat) {
  int idx = blockIdx.x * 256 + threadIdx.x;   // b*N+n
  if (idx >= B_ * N_) return;
  float mx = -1e30f, ls = 0.f;
  #pragma unroll
  for (int z = 0; z < 4; ++z) {
    float2 s = p[(size_t)z * B_ * N_ + idx];
    float mn = fmaxf(mx, s.x);
    ls = ls * fexp2(mx - mn) + s.y * fexp2(s.x - mn);
    mx = mn;
  }
  astat[idx] = -mx - flog2(ls);
}

// ------- pass 2: fused scores+softmax+PV partials; grid 1152 (XCD swizzle) --
// v10: lgkm-only barriers (VMEM prefetch in flight across); bf16 spart;
// s-row sums inside ss-bounce loop.
__global__ __launch_bounds__(256) void k_attn_out(const ushort* __restrict__ f,
                                                  const ushort* __restrict__ g,
                                                  const ushort* __restrict__ h,
                                                  const float* __restrict__ astat,
                                                  ushort* __restrict__ spart,
                                                  float* __restrict__ wcat) {
  __shared__ __align__(16) char smem[32768];
  char* gs = smem;            // [64 m][128 c] SW16 16 KB (staged once)
  char* pTb = smem + 16384;   // pT double buffer 2 x 8 KB
  const int blk = blockIdx.x;
  const int b = blk & 7, t2 = blk >> 3;
  const int m0 = (t2 % 36) * 64, nz = t2 / 36;
  const int t = threadIdx.x, l = t & 63, w = t >> 6, lo = l & 15, quad = l >> 4;
  const ushort* fb = f + (size_t)b * N_ * C_;
  const ushort* gb = g + (size_t)b * N_ * C_;
  const ushort* hb = h + (size_t)b * C_ * N_;
  const float* ab = astat + (size_t)b * N_;
  #pragma unroll
  for (int it = 0; it < 4; ++it) {   // gs: 1024 granules, once
    int G = t + it * 256, row = G >> 4, g16 = G & 15;
    *(u16x8*)(gs + SW16(row, g16)) = *(const u16x8*)(gb + (size_t)(m0 + row) * C_ + g16 * 8);
  }
  f32x4 accs[2][4];
  #pragma unroll
  for (int i = 0; i < 2; ++i)
    #pragma unroll
    for (int j = 0; j < 4; ++j) accs[i][j] = (f32x4)0.f;
  const int n_beg = nz * 576;

  s16x8 af[2][4];
  s16x8 ahc[2][2];
  float ax[2][4];

  auto LOAD_AF = [&](int i, int p) {
    int nb = n_beg + i * 64;
    #pragma unroll
    for (int ks = 0; ks < 4; ++ks)
      af[p][ks] = *(const s16x8*)(fb + (size_t)(nb + w * 16 + lo) * C_ + (ks * 4 + quad) * 8);
    float4 av = *(const float4*)(ab + nb + w * 16 + quad * 4);
    ax[p][0] = av.x; ax[p][1] = av.y; ax[p][2] = av.z; ax[p][3] = av.w;
  };
  auto LOAD_AH = [&](int i) {
    int nb = n_beg + i * 64;
    #pragma unroll
    for (int ii = 0; ii < 2; ++ii)
      #pragma unroll
      for (int ks = 0; ks < 2; ++ks)
        ahc[ii][ks] = *(const s16x8*)(hb + (size_t)((2 * w + ii) * 16 + lo) * N_ + nb + (ks * 4 + quad) * 8);
  };
  auto QKEXP = [&](int p) {
    char* pT = pTb + (p << 13);
    f32x4 sc[4];
    #pragma unroll
    for (int j = 0; j < 4; ++j) sc[j] = (f32x4)0.f;
    __builtin_amdgcn_s_setprio(1);
    #pragma unroll
    for (int ks = 0; ks < 4; ++ks)
      #pragma unroll
      for (int j = 0; j < 4; ++j) {
        s16x8 bg = *(const s16x8*)(gs + SW16(j * 16 + lo, ks * 4 + quad));
        sc[j] = __builtin_amdgcn_mfma_f32_16x16x32_bf16(af[p][ks], bg, sc[j], 0, 0, 0);
      }
    __builtin_amdgcn_s_setprio(0);
    const int nl = w * 16 + quad * 4;
    #pragma unroll
    for (int j = 0; j < 4; ++j) {
      u16x4 pv;
      #pragma unroll
      for (int r = 0; r < 4; ++r)
        pv[r] = f2bf(fexp2(sc[j][r] + ax[p][r]));
      *(u16x4*)(pT + SW8(j * 16 + lo, nl >> 3) + (nl & 7) * 2) = pv;
    }
  };
  auto PV = [&](int p) {
    char* pT = pTb + (p << 13);
    __builtin_amdgcn_s_setprio(1);
    #pragma unroll
    for (int ks = 0; ks < 2; ++ks)
      #pragma unroll
      for (int j = 0; j < 4; ++j) {
        s16x8 bp = *(const s16x8*)(pT + SW8(j * 16 + lo, ks * 4 + quad));
        accs[0][j] = __builtin_amdgcn_mfma_f32_16x16x32_bf16(ahc[0][ks], bp, accs[0][j], 0, 0, 0);
        accs[1][j] = __builtin_amdgcn_mfma_f32_16x16x32_bf16(ahc[1][ks], bp, accs[1][j], 0, 0, 0);
      }
    __builtin_amdgcn_s_setprio(0);
  };

  LOAD_AF(0, 0);
  LOAD_AH(0);
  bar_lgkm();                // gs staged (VMEM prefetch stays in flight)
  QKEXP(0);                  // writes pT[0]
  LOAD_AF(1, 1);
  #pragma unroll
  for (int i9 = 0; i9 < 9; ++i9) {
    bar_lgkm();              // pT[i9&1] published
    PV(i9 & 1);
    if (i9 < 8) {
      LOAD_AH(i9 + 1);
      QKEXP((i9 + 1) & 1);
      if (i9 < 7) LOAD_AF(i9 + 2, i9 & 1);
    }
  }
  // epilogue: two-chunk f32 transpose bounce -> bf16 stores (128 B segments).
  // s-row sums from the f32 values (16 consecutive lanes share ci).
  ushort* outp = spart + (size_t)nz * TOT_OUT + (size_t)b * C_ * N_ + m0;
  float* ss = (float*)smem;   // [64 rows][68] f32 = 17408 B (gs/pT dead)
  #pragma unroll
  for (int ch = 0; ch < 2; ++ch) {
    bar_lgkm();               // pT reads done / prior chunk stores done
    {
      int ci0 = w * 16 + quad * 4;
      #pragma unroll
      for (int j = 0; j < 4; ++j) {
        int m = j * 16 + lo;
        #pragma unroll
        for (int r = 0; r < 4; ++r)
          ss[(ci0 + r) * 68 + m] = accs[ch][j][r];
      }
    }
    bar_lgkm();
    #pragma unroll
    for (int it = 0; it < 4; ++it) {
      int idx = t + it * 256;
      int ci = idx >> 4, mq = idx & 15;
      int c = (ci >> 4) * 32 + ch * 16 + (ci & 15);
      float4 v = *(const float4*)&ss[ci * 68 + mq * 4];
      u16x4 pv;
      pv[0] = f2bf(v.x); pv[1] = f2bf(v.y); pv[2] = f2bf(v.z); pv[3] = f2bf(v.w);
      *(u16x4*)&outp[(size_t)c * N_ + mq * 4] = pv;
      float sm = (v.x + v.y) + (v.z + v.w);
      #pragma unroll
      for (int o = 1; o < 16; o <<= 1) sm += __shfl_xor(sm, o, 64);
      if (mq == 0) atomicAdd(&wcat[(b << 8) + 128 + c], sm);
    }
  }
}

// ---------------- SE MLP: 256 -> 42 (relu) -> 128 ---------------------------
// wcat holds RAW sums both halves: x-sums (prep_y) and s-sums (attn epilogue).
__global__ __launch_bounds__(128) void k_se(const float* __restrict__ wcat,
                                            const float* __restrict__ cw,
                                            const float* __restrict__ cb,
                                            const float* __restrict__ uw,
                                            const float* __restrict__ ub,
                                            float* __restrict__ se) {
  const int b = blockIdx.x, t = threadIdx.x;
  __shared__ float wc[256];
  __shared__ float s1[42];
  wc[t] = fmaxf(wcat[b * 256 + t] * (1.f / PLANE_IN), 0.f);
  wc[128 + t] = fmaxf(wcat[b * 256 + 128 + t] * (1.f / N_), 0.f);
  __syncthreads();
  if (t < 42) {
    float a = cb[t];
    const float* r = cw + (size_t)t * 256;
    for (int k = 0; k < 256; ++k) a += wc[k] * r[k];
    s1[t] = fmaxf(a, 0.f);
  }
  __syncthreads();
  {
    float a = ub[t];
    const float* r = uw + (size_t)t * 42;
    for (int j = 0; j < 42; ++j) a += s1[j] * r[j];
    se[b * 128 + t] = a;
  }
}

// ------- out = (avgpool2x2(x) + sum_z spart_bf16[z]) * (1 + se) -------------
__global__ __launch_bounds__(256) void k_final(const float* __restrict__ x,
                                               const ushort* __restrict__ spart,
                                               const float* __restrict__ se,
                                               float* __restrict__ out) {
  int idx = blockIdx.x * 256 + threadIdx.x;
  if (idx >= TOT_OUT / 2) return;
  int m2 = idx % (N_ / 2);
  int bc = idx / (N_ / 2);
  int oh = m2 / (HO_ / 2), owp = m2 - oh * (HO_ / 2);
  size_t base = (size_t)bc * N_ + oh * HO_ + owp * 2;
  const float* xp = x + (size_t)bc * PLANE_IN;
  int ih = oh * 2, iw = owp * 4;
  float4 a = *(const float4*)(xp + ih * W_ + iw);
  float4 bb = *(const float4*)(xp + (ih + 1) * W_ + iw);
  float l0 = 0.25f * (a.x + a.y + bb.x + bb.y);
  float l1 = 0.25f * (a.z + a.w + bb.z + bb.w);
  u16x2 s0 = *(const u16x2*)(spart + base);
  u16x2 s1 = *(const u16x2*)(spart + (size_t)TOT_OUT + base);
  u16x2 s2 = *(const u16x2*)(spart + 2 * (size_t)TOT_OUT + base);
  u16x2 s3 = *(const u16x2*)(spart + 3 * (size_t)TOT_OUT + base);
  float sc = 1.f + se[bc];
  float2 o;
  o.x = (l0 + bf2f(s0[0]) + bf2f(s1[0]) + bf2f(s2[0]) + bf2f(s3[0])) * sc;
  o.y = (l1 + bf2f(s0[1]) + bf2f(s1[1]) + bf2f(s2[1]) + bf2f(s3[1])) * sc;
  *(float2*)(out + base) = o;
}

extern "C" void kernel_launch(void* const* d_in, const int* in_sizes, int n_in,
                              void* d_out, int out_size, void* d_ws, size_t ws_size,
                              hipStream_t stream) {
  (void)in_sizes; (void)n_in; (void)out_size; (void)ws_size;
  const float* x    = (const float*)d_in[0];
  const float* bnw[3] = {(const float*)d_in[1],  (const float*)d_in[7],  (const float*)d_in[13]};
  const float* bnb[3] = {(const float*)d_in[2],  (const float*)d_in[8],  (const float*)d_in[14]};
  const float* bnm[3] = {(const float*)d_in[3],  (const float*)d_in[9],  (const float*)d_in[15]};
  const float* bnv[3] = {(const float*)d_in[4],  (const float*)d_in[10], (const float*)d_in[16]};
  const float* cw_[3] = {(const float*)d_in[5],  (const float*)d_in[11], (const float*)d_in[17]};
  const float* cbb[3] = {(const float*)d_in[6],  (const float*)d_in[12], (const float*)d_in[18]};
  const float* secw = (const float*)d_in[19];
  const float* secb = (const float*)d_in[20];
  const float* seuw = (const float*)d_in[21];
  const float* seub = (const float*)d_in[22];
  const float* gamma = (const float*)d_in[23];
  float* out = (float*)d_out;

  char* ws = (char*)d_ws;
  size_t off = 0;
  auto alloc = [&](size_t bytes) -> char* {
    char* p = ws + off;
    off = (off + bytes + 255) & ~(size_t)255;
    return p;
  };
  ushort* yp[3];
  for (int p = 0; p < 3; ++p) yp[p] = (ushort*)alloc((size_t)B_ * HP_ * HP_ * C_ * 2);
  ushort* wb[3];
  for (int p = 0; p < 3; ++p) wb[p] = (ushort*)alloc((size_t)C_ * K_CONV * 2);
  ushort* fbuf = (ushort*)alloc((size_t)B_ * N_ * C_ * 2);       // [b][n][c], *log2e
  ushort* gbuf = (ushort*)alloc((size_t)B_ * N_ * C_ * 2);       // [b][n][c]
  ushort* hbuf = (ushort*)alloc((size_t)B_ * C_ * N_ * 2);       // [b][c][n], *gamma
  float2* pstats = (float2*)alloc((size_t)4 * B_ * N_ * 8);      // partial (mx2,l2)
  float*  astat  = (float*)alloc((size_t)B_ * N_ * 4);           // -mx2 - log2(l2)
  ushort* spart = (ushort*)alloc((size_t)4 * TOT_OUT * 2);       // partial PV sums (bf16)
  float*  wcat = (float*)alloc(B_ * 256 * 4);
  float*  sebuf = (float*)alloc(B_ * 128 * 4);
  float*  pinv  = (float*)alloc(3 * 128 * 4);
  float*  pbeta = (float*)alloc(3 * 128 * 4);

  hipMemsetAsync(wcat, 0, B_ * 256 * 4, stream);   // raw-sum accumulators

  k_prep_w<<<dim3((C_ * K_CONV) / 256 + 1, 3), 256, 0, stream>>>(
      cw_[0], cw_[1], cw_[2], wb[0], wb[1], wb[2],
      bnw[0], bnb[0], bnm[0], bnv[0],
      bnw[1], bnb[1], bnm[1], bnv[1],
      bnw[2], bnb[2], bnm[2], bnv[2], pinv, pbeta);
  k_prep_y<<<dim3(HP_, B_), 256, 0, stream>>>(x, pinv, pbeta, yp[0], yp[1], yp[2], wcat);

  k_conv3<<<dim3(N_ / 128, 3, B_), 256, 0, stream>>>(yp[0], yp[1], yp[2],
                                                     wb[0], wb[1], wb[2],
                                                     cbb[0], cbb[1], cbb[2], gamma,
                                                     fbuf, gbuf, hbuf);

  k_stats<<<1152, 256, 0, stream>>>(fbuf, gbuf, pstats);
  k_stats_red<<<(B_ * N_ + 255) / 256, 256, 0, stream>>>(pstats, astat);
  k_attn_out<<<1152, 256, 0, stream>>>(fbuf, gbuf, hbuf, astat, spart, wcat);

  k_se<<<B_, 128, 0, stream>>>(wcat, secw, secb, seuw, seub, sebuf);

  k_final<<<(TOT_OUT / 2 + 255) / 256, 256, 0, stream>>>(x, spart, sebuf, out);
}